// Round 7
// baseline (319.381 us; speedup 1.0000x reference)
//
#include <hip/hip_runtime.h>

#define NN 20000
#define EE 660000      // 640000 + 20000 self loops
#define GG 64
#define FIN 114
#define H1 3
#define F1 342         // H1*FIN
#define D2 128
#define NEG 0.2f
#define H1AS 352       // h1aP row stride (342 padded, cols 342..351 zero)

__device__ inline unsigned fenc(float f) {
    unsigned u = __float_as_uint(f);
    return (u & 0x80000000u) ? ~u : (u | 0x80000000u);
}
__device__ inline float fdec(unsigned u) {
    return (u & 0x80000000u) ? __uint_as_float(u & 0x7FFFFFFFu) : __uint_as_float(~u);
}
__device__ inline float lrelu(float x) { return x > 0.f ? x : NEG * x; }

// ===== fold a_src/a_dst through W1 =====
__global__ void k_wa(const float* __restrict__ W1, const float* __restrict__ aS,
                     const float* __restrict__ aD, float* __restrict__ was,
                     float* __restrict__ wad) {
    int tid = blockIdx.x * 256 + threadIdx.x;
    if (tid >= 2 * FIN * H1) return;
    int which = tid >= FIN * H1;
    int i = which ? tid - FIN * H1 : tid;
    int k = i / H1, h = i % H1;
    const float* a = which ? aD : aS;
    float s = 0.f;
    for (int d = 0; d < FIN; d++) s += W1[k * F1 + h * FIN + d] * a[h * FIN + d];
    (which ? wad : was)[i] = s;
}

// ===== W1 prep: W1P[h][k][c], k and c padded to 128 with zeros =====
__global__ void k_prep1(const float* __restrict__ W1, float* __restrict__ W1P) {
    int tid = blockIdx.x * 256 + threadIdx.x;
    if (tid >= H1 * 128 * 128) return;
    int h = tid / (128 * 128);
    int rem = tid & (128 * 128 - 1);
    int k = rem >> 7, c = rem & 127;
    W1P[tid] = (c < FIN && k < FIN) ? W1[k * F1 + h * FIN + c] : 0.f;
}

// ===== as1/ad1 = x @ was/wad =====
__global__ __launch_bounds__(256) void k_alpha1x(const float* __restrict__ x,
                                                 const float* __restrict__ was,
                                                 const float* __restrict__ wad,
                                                 float* __restrict__ as1,
                                                 float* __restrict__ ad1) {
    int n = blockIdx.x * 4 + (threadIdx.x >> 6);
    int l = threadIdx.x & 63;
    if (n >= NN) return;
    float x0 = x[n * FIN + l];
    float x1 = (l < FIN - 64) ? x[n * FIN + 64 + l] : 0.f;
    float s[H1], d[H1];
#pragma unroll
    for (int h = 0; h < H1; h++) {
        float w0s = was[l * H1 + h], w0d = wad[l * H1 + h];
        float w1s = (l < FIN - 64) ? was[(64 + l) * H1 + h] : 0.f;
        float w1d = (l < FIN - 64) ? wad[(64 + l) * H1 + h] : 0.f;
        s[h] = x0 * w0s + x1 * w1s;
        d[h] = x0 * w0d + x1 * w1d;
    }
#pragma unroll
    for (int o = 32; o > 0; o >>= 1) {
#pragma unroll
        for (int h = 0; h < H1; h++) {
            s[h] += __shfl_down(s[h], o);
            d[h] += __shfl_down(d[h], o);
        }
    }
    if (l == 0) {
#pragma unroll
        for (int h = 0; h < H1; h++) {
            as1[n * H1 + h] = s[h];
            ad1[n * H1 + h] = d[h];
        }
    }
}

// ===================== CSR build =====================
__global__ void k_count(const int* __restrict__ dst, int* __restrict__ cnt) {
    int e = blockIdx.x * 256 + threadIdx.x;
    if (e < EE) atomicAdd(&cnt[dst[e]], 1);
}

__global__ __launch_bounds__(1024) void k_scan(const int* __restrict__ cnt,
                                               int* __restrict__ off) {
    __shared__ int part[1024];
    int t = threadIdx.x;
    const int CH = 20;
    int loc[CH];
    int s = 0;
    int base = t * CH;
    for (int i = 0; i < CH; i++) {
        int idx = base + i;
        int v = (idx < NN) ? cnt[idx] : 0;
        loc[i] = s;
        s += v;
    }
    part[t] = s;
    __syncthreads();
    for (int d = 1; d < 1024; d <<= 1) {
        int v = (t >= d) ? part[t - d] : 0;
        __syncthreads();
        part[t] += v;
        __syncthreads();
    }
    int pre = (t == 0) ? 0 : part[t - 1];
    for (int i = 0; i < CH; i++) {
        int idx = base + i;
        if (idx < NN) off[idx] = pre + loc[i];
    }
    if (t == 1023) off[NN] = part[1023];
}

__global__ void k_scatter(const int* __restrict__ src, const int* __restrict__ dst,
                          const int* __restrict__ off, int* __restrict__ cur,
                          int* __restrict__ csr_src) {
    int e = blockIdx.x * 256 + threadIdx.x;
    if (e < EE) {
        int d = dst[e];
        int pos = off[d] + atomicAdd(&cur[d], 1);
        csr_src[pos] = src[e];
    }
}

// ===== layer-1: fused softmax+aggregate of x into xaggP[3][N][128] (zero-padded) =====
__global__ __launch_bounds__(128) void k_aggx(const float* __restrict__ x,
                                              const float* __restrict__ as1,
                                              const float* __restrict__ ad1,
                                              const int* __restrict__ off,
                                              const int* __restrict__ csr_src,
                                              float* __restrict__ xaggP) {
    int n = blockIdx.x, t = threadIdx.x;
    int e0 = off[n], e1 = off[n + 1];
    float adv0 = ad1[n * H1 + 0], adv1 = ad1[n * H1 + 1], adv2 = ad1[n * H1 + 2];
    __shared__ int ssrc[64];
    __shared__ float sw[64][H1];
    __shared__ float red[64][H1];
    float acc0 = 0.f, acc1 = 0.f, acc2 = 0.f;
    float ps0 = 0.f, ps1 = 0.f, ps2 = 0.f;
    for (int base = e0; base < e1; base += 64) {
        int c = min(64, e1 - base);
        __syncthreads();
        if (t < c) {
            int s = csr_src[base + t];
            ssrc[t] = s;
            float w0 = __expf(lrelu(as1[s * H1 + 0] + adv0));
            float w1 = __expf(lrelu(as1[s * H1 + 1] + adv1));
            float w2 = __expf(lrelu(as1[s * H1 + 2] + adv2));
            sw[t][0] = w0; sw[t][1] = w1; sw[t][2] = w2;
            ps0 += w0; ps1 += w1; ps2 += w2;
        }
        __syncthreads();
        if (t < FIN) {
            for (int j = 0; j < c; j++) {
                float xv = x[ssrc[j] * FIN + t];
                acc0 += xv * sw[j][0];
                acc1 += xv * sw[j][1];
                acc2 += xv * sw[j][2];
            }
        }
    }
    __syncthreads();
    if (t < 64) { red[t][0] = ps0; red[t][1] = ps1; red[t][2] = ps2; }
    __syncthreads();
    for (int sr = 32; sr > 0; sr >>= 1) {
        if (t < sr) {
            red[t][0] += red[t + sr][0];
            red[t][1] += red[t + sr][1];
            red[t][2] += red[t + sr][2];
        }
        __syncthreads();
    }
    float i0 = 1.f / red[0][0], i1 = 1.f / red[0][1], i2 = 1.f / red[0][2];
    float v0 = (t < FIN) ? acc0 * i0 : 0.f;
    float v1 = (t < FIN) ? acc1 * i1 : 0.f;
    float v2 = (t < FIN) ? acc2 * i2 : 0.f;
    xaggP[(size_t)0 * NN * 128 + n * 128 + t] = v0;
    xaggP[(size_t)1 * NN * 128 + n * 128 + t] = v1;
    xaggP[(size_t)2 * NN * 128 + n * 128 + t] = v2;
}

// ===== GEMM1 tiled: h1aP = ELU(xaggP_h @ W1_h + b1) =====
// grid (313,3), 256 thr; BM=64, BN=128, BK=32 (K=128 padded, 4 tiles).
// As[64][36] row-major (conflict-free b128); reg-prefetch double buffer.
__global__ __launch_bounds__(256) void k_gemm1t(const float* __restrict__ xaggP,
                                                const float* __restrict__ W1P,
                                                const float* __restrict__ b1,
                                                float* __restrict__ h1aP) {
    int h = blockIdx.y;
    int rb = blockIdx.x * 64;
    int t = threadIdx.x;
    int tr = t >> 4, tc = t & 15;
    __shared__ float As[64][36];
    __shared__ float Bs[32][132];
    const float* Ap = xaggP + (size_t)h * NN * 128;
    const float* Bp = W1P + (size_t)h * 128 * 128;
    const float4 zf4 = make_float4(0.f, 0.f, 0.f, 0.f);

    int ar0 = t >> 3, ak0 = t & 7;   // q0: rows 0..31
    int ar1 = 32 + ar0;              // q1: rows 32..63
    int bk[4], bn[4];
#pragma unroll
    for (int q = 0; q < 4; q++) { int idd = t + q * 256; bk[q] = idd >> 5; bn[q] = idd & 31; }

    float4 aR[2], bR[4];
    {
        int g0 = rb + ar0, g1 = rb + ar1;
        aR[0] = (g0 < NN) ? *(const float4*)(Ap + (size_t)g0 * 128 + ak0 * 4) : zf4;
        aR[1] = (g1 < NN) ? *(const float4*)(Ap + (size_t)g1 * 128 + ak0 * 4) : zf4;
#pragma unroll
        for (int q = 0; q < 4; q++)
            bR[q] = *(const float4*)(Bp + (size_t)bk[q] * 128 + bn[q] * 4);
    }
    float acc[4][8] = {};
    for (int tile = 0; tile < 4; tile++) {
        if (tile) __syncthreads();
        *(float4*)(&As[ar0][ak0 * 4]) = aR[0];
        *(float4*)(&As[ar1][ak0 * 4]) = aR[1];
#pragma unroll
        for (int q = 0; q < 4; q++) *(float4*)(&Bs[bk[q]][bn[q] * 4]) = bR[q];
        __syncthreads();
        if (tile < 3) {
            int k0 = (tile + 1) * 32;
            int g0 = rb + ar0, g1 = rb + ar1;
            aR[0] = (g0 < NN) ? *(const float4*)(Ap + (size_t)g0 * 128 + k0 + ak0 * 4) : zf4;
            aR[1] = (g1 < NN) ? *(const float4*)(Ap + (size_t)g1 * 128 + k0 + ak0 * 4) : zf4;
#pragma unroll
            for (int q = 0; q < 4; q++)
                bR[q] = *(const float4*)(Bp + (size_t)(k0 + bk[q]) * 128 + bn[q] * 4);
        }
#pragma unroll
        for (int kc = 0; kc < 32; kc += 4) {
            float a4[4][4];
#pragma unroll
            for (int r = 0; r < 4; r++)
                *(float4*)a4[r] = *(const float4*)(&As[tr * 4 + r][kc]);
#pragma unroll
            for (int kk = 0; kk < 4; kk++) {
                float4 b0 = *(const float4*)(&Bs[kc + kk][tc * 4]);
                float4 b1v = *(const float4*)(&Bs[kc + kk][64 + tc * 4]);
#pragma unroll
                for (int r = 0; r < 4; r++) {
                    float av = a4[r][kk];
                    acc[r][0] += av * b0.x;  acc[r][1] += av * b0.y;
                    acc[r][2] += av * b0.z;  acc[r][3] += av * b0.w;
                    acc[r][4] += av * b1v.x; acc[r][5] += av * b1v.y;
                    acc[r][6] += av * b1v.z; acc[r][7] += av * b1v.w;
                }
            }
        }
    }
    int hb = h * FIN;
#pragma unroll
    for (int r = 0; r < 4; r++) {
        int row = rb + tr * 4 + r;
        if (row >= NN) continue;
        float* orow = h1aP + (size_t)row * H1AS + hb;
#pragma unroll
        for (int j = 0; j < 8; j++) {
            int c = (j < 4) ? (tc * 4 + j) : (64 + tc * 4 + (j - 4));
            if (c < FIN) {
                float v = acc[r][j] + b1[hb + c];
                orow[c] = v > 0.f ? v : expm1f(v);
            } else if (h == 2 && c < 124) {
                orow[c] = 0.f;   // zero-pad h1aP cols 342..351
            }
        }
    }
}

// ===== GEMM2 tiled: h2 = h1aP @ W2 =====
// grid 626 (mt = bx>>1, nb = (bx&1)*64), 256 thr; BM=64, BN=64, BK=32, 11 tiles.
__global__ __launch_bounds__(256) void k_gemm2t(const float* __restrict__ h1aP,
                                                const float* __restrict__ W2,
                                                float* __restrict__ h2) {
    int mt = blockIdx.x >> 1, nb = (blockIdx.x & 1) * 64;
    int rb = mt * 64;
    int t = threadIdx.x;
    int tr = t >> 4, tc = t & 15;
    __shared__ float As[64][36];
    __shared__ float Bs[32][68];
    const float4 zf4 = make_float4(0.f, 0.f, 0.f, 0.f);
    int ar0 = t >> 3, ak0 = t & 7;
    int ar1 = 32 + ar0;
    int bk0 = t >> 4, bn0 = t & 15;
    int bk1 = 16 + bk0;
    float4 aR[2], bR[2];
    {
        int g0 = rb + ar0, g1 = rb + ar1;
        aR[0] = (g0 < NN) ? *(const float4*)(h1aP + (size_t)g0 * H1AS + ak0 * 4) : zf4;
        aR[1] = (g1 < NN) ? *(const float4*)(h1aP + (size_t)g1 * H1AS + ak0 * 4) : zf4;
        bR[0] = *(const float4*)(W2 + (size_t)bk0 * D2 + nb + bn0 * 4);
        bR[1] = *(const float4*)(W2 + (size_t)bk1 * D2 + nb + bn0 * 4);
    }
    float acc[4][4] = {};
    for (int tile = 0; tile < 11; tile++) {
        if (tile) __syncthreads();
        *(float4*)(&As[ar0][ak0 * 4]) = aR[0];
        *(float4*)(&As[ar1][ak0 * 4]) = aR[1];
        *(float4*)(&Bs[bk0][bn0 * 4]) = bR[0];
        *(float4*)(&Bs[bk1][bn0 * 4]) = bR[1];
        __syncthreads();
        if (tile < 10) {
            int k0 = (tile + 1) * 32;
            int g0 = rb + ar0, g1 = rb + ar1;
            aR[0] = (g0 < NN) ? *(const float4*)(h1aP + (size_t)g0 * H1AS + k0 + ak0 * 4) : zf4;
            aR[1] = (g1 < NN) ? *(const float4*)(h1aP + (size_t)g1 * H1AS + k0 + ak0 * 4) : zf4;
            bR[0] = (k0 + bk0 < F1) ? *(const float4*)(W2 + (size_t)(k0 + bk0) * D2 + nb + bn0 * 4) : zf4;
            bR[1] = (k0 + bk1 < F1) ? *(const float4*)(W2 + (size_t)(k0 + bk1) * D2 + nb + bn0 * 4) : zf4;
        }
#pragma unroll
        for (int kc = 0; kc < 32; kc += 4) {
            float a4[4][4];
#pragma unroll
            for (int r = 0; r < 4; r++)
                *(float4*)a4[r] = *(const float4*)(&As[tr * 4 + r][kc]);
#pragma unroll
            for (int kk = 0; kk < 4; kk++) {
                float4 b0 = *(const float4*)(&Bs[kc + kk][tc * 4]);
#pragma unroll
                for (int r = 0; r < 4; r++) {
                    float av = a4[r][kk];
                    acc[r][0] += av * b0.x; acc[r][1] += av * b0.y;
                    acc[r][2] += av * b0.z; acc[r][3] += av * b0.w;
                }
            }
        }
    }
#pragma unroll
    for (int r = 0; r < 4; r++) {
        int row = rb + tr * 4 + r;
        if (row < NN)
            *(float4*)(&h2[(size_t)row * D2 + nb + tc * 4]) =
                make_float4(acc[r][0], acc[r][1], acc[r][2], acc[r][3]);
    }
}

// ===== alpha2: per-node dot(h2_row, a_src2/a_dst2) =====
__global__ __launch_bounds__(256) void k_alpha2(const float* __restrict__ h2,
                                                const float* __restrict__ aS,
                                                const float* __restrict__ aD,
                                                float* __restrict__ as2,
                                                float* __restrict__ ad2) {
    int n = blockIdx.x * 4 + (threadIdx.x >> 6);
    int l = threadIdx.x & 63;
    if (n >= NN) return;
    float v0 = h2[(size_t)n * D2 + l], v1 = h2[(size_t)n * D2 + 64 + l];
    float ps = v0 * aS[l] + v1 * aS[64 + l];
    float pd = v0 * aD[l] + v1 * aD[64 + l];
    for (int o = 32; o > 0; o >>= 1) {
        ps += __shfl_down(ps, o);
        pd += __shfl_down(pd, o);
    }
    if (l == 0) {
        as2[n] = ps;
        ad2[n] = pd;
    }
}

// ===== layer-2: fused softmax+aggregate+relu+POOL (atomicMax into poolbuf) =====
__global__ __launch_bounds__(128) void k_agg2f(const float* __restrict__ h2,
                                               const float* __restrict__ as2,
                                               const float* __restrict__ ad2,
                                               const int* __restrict__ off,
                                               const int* __restrict__ csr_src,
                                               const float* __restrict__ b2,
                                               unsigned* __restrict__ poolbuf) {
    int n = blockIdx.x, t = threadIdx.x;
    int e0 = off[n], e1 = off[n + 1];
    float adv = ad2[n];
    __shared__ int ssrc[64];
    __shared__ float sw[64];
    __shared__ float red[64];
    float acc = 0.f, ps = 0.f;
    for (int base = e0; base < e1; base += 64) {
        int c = min(64, e1 - base);
        __syncthreads();
        if (t < c) {
            int s = csr_src[base + t];
            ssrc[t] = s;
            float w = __expf(lrelu(as2[s] + adv));
            sw[t] = w;
            ps += w;
        }
        __syncthreads();
        for (int j = 0; j < c; j++) acc += h2[(size_t)ssrc[j] * D2 + t] * sw[j];
    }
    __syncthreads();
    if (t < 64) red[t] = ps;
    __syncthreads();
    for (int sr = 32; sr > 0; sr >>= 1) {
        if (t < sr) red[t] += red[t + sr];
        __syncthreads();
    }
    float v = fmaxf(acc / red[0] + b2[t], 0.f);
    int g = (int)(((long long)n * GG) / NN);   // batch[n] = n*G//N
    atomicMax(&poolbuf[g * D2 + t], fenc(v));
}

// ===== MLP head =====
__global__ __launch_bounds__(128) void k_mlp(const unsigned* __restrict__ poolbuf,
                                             const float* __restrict__ Wg,
                                             const float* __restrict__ bg,
                                             const float* __restrict__ Wf1,
                                             const float* __restrict__ bf1,
                                             const float* __restrict__ Wf2,
                                             const float* __restrict__ bf2,
                                             const float* __restrict__ Wo,
                                             const float* __restrict__ bo,
                                             float* __restrict__ out) {
    int g = blockIdx.x;
    int t = threadIdx.x;
    __shared__ float pool[D2];
    __shared__ float a1[64];
    __shared__ float a2[32];
    __shared__ float a3[16];
    pool[t] = fdec(poolbuf[g * D2 + t]);
    __syncthreads();
    if (t < 64) {
        float acc = bg[t];
        for (int k = 0; k < D2; k++) acc += pool[k] * Wg[k * 64 + t];
        a1[t] = fmaxf(acc, 0.f);
    }
    __syncthreads();
    if (t < 32) {
        float acc = bf1[t];
        for (int k = 0; k < 64; k++) acc += a1[k] * Wf1[k * 32 + t];
        a2[t] = fmaxf(acc, 0.f);
    }
    __syncthreads();
    if (t < 16) {
        float acc = bf2[t];
        for (int k = 0; k < 32; k++) acc += a2[k] * Wf2[k * 16 + t];
        a3[t] = fmaxf(acc, 0.f);
    }
    __syncthreads();
    if (t == 0) {
        float acc = bo[0];
        for (int k = 0; k < 16; k++) acc += a3[k] * Wo[k];
        out[g] = acc;
    }
}

extern "C" void kernel_launch(void* const* d_in, const int* in_sizes, int n_in,
                              void* d_out, int out_size, void* d_ws, size_t ws_size,
                              hipStream_t stream) {
    const float* x = (const float*)d_in[0];
    const int* ei = (const int*)d_in[1];
    const float* W1 = (const float*)d_in[3];
    const float* aS1 = (const float*)d_in[4];
    const float* aD1 = (const float*)d_in[5];
    const float* b1 = (const float*)d_in[6];
    const float* W2 = (const float*)d_in[7];
    const float* aS2 = (const float*)d_in[8];
    const float* aD2 = (const float*)d_in[9];
    const float* b2 = (const float*)d_in[10];
    const float* Wg = (const float*)d_in[11];
    const float* bg = (const float*)d_in[12];
    const float* Wf1 = (const float*)d_in[13];
    const float* bf1 = (const float*)d_in[14];
    const float* Wf2 = (const float*)d_in[15];
    const float* bf2 = (const float*)d_in[16];
    const float* Wo = (const float*)d_in[17];
    const float* bo = (const float*)d_in[18];
    float* out = (float*)d_out;

    const int* src = ei;
    const int* dst = ei + EE;

    char* ws = (char*)d_ws;
    size_t o = 0;
    auto alloc = [&](size_t bytes) -> char* {
        char* p = ws + o;
        o += (bytes + 255) & ~(size_t)255;
        return p;
    };
    float* was = (float*)alloc((size_t)FIN * H1 * 4);
    float* wad = (float*)alloc((size_t)FIN * H1 * 4);
    float* W1P = (float*)alloc((size_t)H1 * 128 * 128 * 4);
    float* as1 = (float*)alloc((size_t)NN * H1 * 4);
    float* ad1 = (float*)alloc((size_t)NN * H1 * 4);
    int* cnt = (int*)alloc((size_t)NN * 4);
    int* off = (int*)alloc((size_t)(NN + 1) * 4);
    int* cur = (int*)alloc((size_t)NN * 4);
    int* csr_src = (int*)alloc((size_t)EE * 4);
    float* xaggP = (float*)alloc((size_t)H1 * NN * 128 * 4);
    float* h1aP = (float*)alloc((size_t)NN * H1AS * 4);
    float* h2 = (float*)alloc((size_t)NN * D2 * 4);
    float* as2 = (float*)alloc((size_t)NN * 4);
    float* ad2 = (float*)alloc((size_t)NN * 4);
    unsigned* poolbuf = (unsigned*)alloc((size_t)GG * D2 * 4);
    (void)ws_size;

    hipMemsetAsync(cnt, 0, (size_t)NN * 4, stream);
    hipMemsetAsync(cur, 0, (size_t)NN * 4, stream);
    hipMemsetAsync(poolbuf, 0, (size_t)GG * D2 * 4, stream);

    const int EB = (EE + 255) / 256;

    k_wa<<<(2 * FIN * H1 + 255) / 256, 256, 0, stream>>>(W1, aS1, aD1, was, wad);
    k_prep1<<<(H1 * 128 * 128 + 255) / 256, 256, 0, stream>>>(W1, W1P);
    k_alpha1x<<<(NN + 3) / 4, 256, 0, stream>>>(x, was, wad, as1, ad1);
    k_count<<<EB, 256, 0, stream>>>(dst, cnt);
    k_scan<<<1, 1024, 0, stream>>>(cnt, off);
    k_scatter<<<EB, 256, 0, stream>>>(src, dst, off, cur, csr_src);
    k_aggx<<<NN, 128, 0, stream>>>(x, as1, ad1, off, csr_src, xaggP);
    k_gemm1t<<<dim3((NN + 63) / 64, H1), 256, 0, stream>>>(xaggP, W1P, b1, h1aP);
    k_gemm2t<<<((NN + 63) / 64) * 2, 256, 0, stream>>>(h1aP, W2, h2);
    k_alpha2<<<(NN + 3) / 4, 256, 0, stream>>>(h2, aS2, aD2, as2, ad2);
    k_agg2f<<<NN, 128, 0, stream>>>(h2, as2, ad2, off, csr_src, b2, poolbuf);
    k_mlp<<<GG, 128, 0, stream>>>(poolbuf, Wg, bg, Wf1, bf1, Wf2, bf2, Wo, bo, out);
}

// Round 8
// 317.360 us; speedup vs baseline: 1.0064x; 1.0064x over previous
//
#include <hip/hip_runtime.h>

#define NN 20000
#define EE 660000      // 640000 + 20000 self loops
#define GG 64
#define FIN 114
#define H1 3
#define F1 342         // H1*FIN
#define D2 128
#define NEG 0.2f

__device__ inline unsigned fenc(float f) {
    unsigned u = __float_as_uint(f);
    return (u & 0x80000000u) ? ~u : (u | 0x80000000u);
}
__device__ inline float fdec(unsigned u) {
    return (u & 0x80000000u) ? __uint_as_float(u & 0x7FFFFFFFu) : __uint_as_float(~u);
}
__device__ inline float lrelu(float x) { return x > 0.f ? x : NEG * x; }

// ===== fold a_src/a_dst through W1 =====
__global__ void k_wa(const float* __restrict__ W1, const float* __restrict__ aS,
                     const float* __restrict__ aD, float* __restrict__ was,
                     float* __restrict__ wad) {
    int tid = blockIdx.x * 256 + threadIdx.x;
    if (tid >= 2 * FIN * H1) return;
    int which = tid >= FIN * H1;
    int i = which ? tid - FIN * H1 : tid;
    int k = i / H1, h = i % H1;
    const float* a = which ? aD : aS;
    float s = 0.f;
    for (int d = 0; d < FIN; d++) s += W1[k * F1 + h * FIN + d] * a[h * FIN + d];
    (which ? wad : was)[i] = s;
}

// ===== W1 prep: W1P[h][k][c], k,c padded to 128 with zeros =====
__global__ void k_prep1(const float* __restrict__ W1, float* __restrict__ W1P) {
    int tid = blockIdx.x * 256 + threadIdx.x;
    if (tid >= H1 * 128 * 128) return;
    int h = tid / (128 * 128);
    int rem = tid & (128 * 128 - 1);
    int k = rem >> 7, c = rem & 127;
    W1P[tid] = (c < FIN && k < FIN) ? W1[k * F1 + h * FIN + c] : 0.f;
}

// ===== W2 prep: W2P[h*128+k][c] = W2[(h*114+k)*128+c], k<114 else 0 (K padded 384) =====
__global__ void k_prep2(const float* __restrict__ W2, float* __restrict__ W2P) {
    int tid = blockIdx.x * 256 + threadIdx.x;
    if (tid >= 3 * 128 * 128) return;
    int hk = tid >> 7, c = tid & 127;
    int h = hk >> 7, k = hk & 127;
    W2P[tid] = (k < FIN) ? W2[(h * FIN + k) * D2 + c] : 0.f;
}

// ===== as1/ad1 = x @ was/wad =====
__global__ __launch_bounds__(256) void k_alpha1x(const float* __restrict__ x,
                                                 const float* __restrict__ was,
                                                 const float* __restrict__ wad,
                                                 float* __restrict__ as1,
                                                 float* __restrict__ ad1) {
    int n = blockIdx.x * 4 + (threadIdx.x >> 6);
    int l = threadIdx.x & 63;
    if (n >= NN) return;
    float x0 = x[n * FIN + l];
    float x1 = (l < FIN - 64) ? x[n * FIN + 64 + l] : 0.f;
    float s[H1], d[H1];
#pragma unroll
    for (int h = 0; h < H1; h++) {
        float w0s = was[l * H1 + h], w0d = wad[l * H1 + h];
        float w1s = (l < FIN - 64) ? was[(64 + l) * H1 + h] : 0.f;
        float w1d = (l < FIN - 64) ? wad[(64 + l) * H1 + h] : 0.f;
        s[h] = x0 * w0s + x1 * w1s;
        d[h] = x0 * w0d + x1 * w1d;
    }
#pragma unroll
    for (int o = 32; o > 0; o >>= 1) {
#pragma unroll
        for (int h = 0; h < H1; h++) {
            s[h] += __shfl_down(s[h], o);
            d[h] += __shfl_down(d[h], o);
        }
    }
    if (l == 0) {
#pragma unroll
        for (int h = 0; h < H1; h++) {
            as1[n * H1 + h] = s[h];
            ad1[n * H1 + h] = d[h];
        }
    }
}

// ===================== CSR build =====================
__global__ void k_count(const int* __restrict__ dst, int* __restrict__ cnt) {
    int e = blockIdx.x * 256 + threadIdx.x;
    if (e < EE) atomicAdd(&cnt[dst[e]], 1);
}

__global__ __launch_bounds__(1024) void k_scan(const int* __restrict__ cnt,
                                               int* __restrict__ off) {
    __shared__ int part[1024];
    int t = threadIdx.x;
    const int CH = 20;
    int loc[CH];
    int s = 0;
    int base = t * CH;
    for (int i = 0; i < CH; i++) {
        int idx = base + i;
        int v = (idx < NN) ? cnt[idx] : 0;
        loc[i] = s;
        s += v;
    }
    part[t] = s;
    __syncthreads();
    for (int d = 1; d < 1024; d <<= 1) {
        int v = (t >= d) ? part[t - d] : 0;
        __syncthreads();
        part[t] += v;
        __syncthreads();
    }
    int pre = (t == 0) ? 0 : part[t - 1];
    for (int i = 0; i < CH; i++) {
        int idx = base + i;
        if (idx < NN) off[idx] = pre + loc[i];
    }
    if (t == 1023) off[NN] = part[1023];
}

__global__ void k_scatter(const int* __restrict__ src, const int* __restrict__ dst,
                          const int* __restrict__ off, int* __restrict__ cur,
                          int* __restrict__ csr_src) {
    int e = blockIdx.x * 256 + threadIdx.x;
    if (e < EE) {
        int d = dst[e];
        int pos = off[d] + atomicAdd(&cur[d], 1);
        csr_src[pos] = src[e];
    }
}

// ===== layer-1: fused softmax+aggregate of x into xaggP[3][N][128] (zero-padded) =====
__global__ __launch_bounds__(128) void k_aggx(const float* __restrict__ x,
                                              const float* __restrict__ as1,
                                              const float* __restrict__ ad1,
                                              const int* __restrict__ off,
                                              const int* __restrict__ csr_src,
                                              float* __restrict__ xaggP) {
    int n = blockIdx.x, t = threadIdx.x;
    int e0 = off[n], e1 = off[n + 1];
    float adv0 = ad1[n * H1 + 0], adv1 = ad1[n * H1 + 1], adv2 = ad1[n * H1 + 2];
    __shared__ int ssrc[64];
    __shared__ float sw[64][H1];
    __shared__ float red[64][H1];
    float acc0 = 0.f, acc1 = 0.f, acc2 = 0.f;
    float ps0 = 0.f, ps1 = 0.f, ps2 = 0.f;
    for (int base = e0; base < e1; base += 64) {
        int c = min(64, e1 - base);
        __syncthreads();
        if (t < c) {
            int s = csr_src[base + t];
            ssrc[t] = s;
            float w0 = __expf(lrelu(as1[s * H1 + 0] + adv0));
            float w1 = __expf(lrelu(as1[s * H1 + 1] + adv1));
            float w2 = __expf(lrelu(as1[s * H1 + 2] + adv2));
            sw[t][0] = w0; sw[t][1] = w1; sw[t][2] = w2;
            ps0 += w0; ps1 += w1; ps2 += w2;
        }
        __syncthreads();
        if (t < FIN) {
            for (int j = 0; j < c; j++) {
                float xv = x[ssrc[j] * FIN + t];
                acc0 += xv * sw[j][0];
                acc1 += xv * sw[j][1];
                acc2 += xv * sw[j][2];
            }
        }
    }
    __syncthreads();
    if (t < 64) { red[t][0] = ps0; red[t][1] = ps1; red[t][2] = ps2; }
    __syncthreads();
    for (int sr = 32; sr > 0; sr >>= 1) {
        if (t < sr) {
            red[t][0] += red[t + sr][0];
            red[t][1] += red[t + sr][1];
            red[t][2] += red[t + sr][2];
        }
        __syncthreads();
    }
    float i0 = 1.f / red[0][0], i1 = 1.f / red[0][1], i2 = 1.f / red[0][2];
    float v0 = (t < FIN) ? acc0 * i0 : 0.f;
    float v1 = (t < FIN) ? acc1 * i1 : 0.f;
    float v2 = (t < FIN) ? acc2 * i2 : 0.f;
    xaggP[(size_t)0 * NN * 128 + n * 128 + t] = v0;
    xaggP[(size_t)1 * NN * 128 + n * 128 + t] = v1;
    xaggP[(size_t)2 * NN * 128 + n * 128 + t] = v2;
}

// ===== GEMM1 tiled: h1aP[h][n][0..127] = ELU(xaggP_h @ W1_h + b1) (pad cols zero) =====
// grid (313,3), 256 thr; BM=64, BN=128, BK=32 (4 tiles); float4 epilogue stores.
__global__ __launch_bounds__(256) void k_gemm1t(const float* __restrict__ xaggP,
                                                const float* __restrict__ W1P,
                                                const float* __restrict__ b1,
                                                float* __restrict__ h1aP) {
    int h = blockIdx.y;
    int rb = blockIdx.x * 64;
    int t = threadIdx.x;
    int tr = t >> 4, tc = t & 15;
    __shared__ float As[64][36];
    __shared__ float Bs[32][132];
    const float* Ap = xaggP + (size_t)h * NN * 128;
    const float* Bp = W1P + (size_t)h * 128 * 128;
    const float4 zf4 = make_float4(0.f, 0.f, 0.f, 0.f);

    int ar0 = t >> 3, ak0 = t & 7;
    int ar1 = 32 + ar0;
    int bk[4], bn[4];
#pragma unroll
    for (int q = 0; q < 4; q++) { int idd = t + q * 256; bk[q] = idd >> 5; bn[q] = idd & 31; }

    float4 aR[2], bR[4];
    {
        int g0 = rb + ar0, g1 = rb + ar1;
        aR[0] = (g0 < NN) ? *(const float4*)(Ap + (size_t)g0 * 128 + ak0 * 4) : zf4;
        aR[1] = (g1 < NN) ? *(const float4*)(Ap + (size_t)g1 * 128 + ak0 * 4) : zf4;
#pragma unroll
        for (int q = 0; q < 4; q++)
            bR[q] = *(const float4*)(Bp + (size_t)bk[q] * 128 + bn[q] * 4);
    }
    float acc[4][8] = {};
    for (int tile = 0; tile < 4; tile++) {
        if (tile) __syncthreads();
        *(float4*)(&As[ar0][ak0 * 4]) = aR[0];
        *(float4*)(&As[ar1][ak0 * 4]) = aR[1];
#pragma unroll
        for (int q = 0; q < 4; q++) *(float4*)(&Bs[bk[q]][bn[q] * 4]) = bR[q];
        __syncthreads();
        if (tile < 3) {
            int k0 = (tile + 1) * 32;
            int g0 = rb + ar0, g1 = rb + ar1;
            aR[0] = (g0 < NN) ? *(const float4*)(Ap + (size_t)g0 * 128 + k0 + ak0 * 4) : zf4;
            aR[1] = (g1 < NN) ? *(const float4*)(Ap + (size_t)g1 * 128 + k0 + ak0 * 4) : zf4;
#pragma unroll
            for (int q = 0; q < 4; q++)
                bR[q] = *(const float4*)(Bp + (size_t)(k0 + bk[q]) * 128 + bn[q] * 4);
        }
#pragma unroll
        for (int kc = 0; kc < 32; kc += 4) {
            float a4[4][4];
#pragma unroll
            for (int r = 0; r < 4; r++)
                *(float4*)a4[r] = *(const float4*)(&As[tr * 4 + r][kc]);
#pragma unroll
            for (int kk = 0; kk < 4; kk++) {
                float4 b0 = *(const float4*)(&Bs[kc + kk][tc * 4]);
                float4 b1v = *(const float4*)(&Bs[kc + kk][64 + tc * 4]);
#pragma unroll
                for (int r = 0; r < 4; r++) {
                    float av = a4[r][kk];
                    acc[r][0] += av * b0.x;  acc[r][1] += av * b0.y;
                    acc[r][2] += av * b0.z;  acc[r][3] += av * b0.w;
                    acc[r][4] += av * b1v.x; acc[r][5] += av * b1v.y;
                    acc[r][6] += av * b1v.z; acc[r][7] += av * b1v.w;
                }
            }
        }
    }
    // epilogue: bias + ELU, pad cols -> 0, float4 stores into h1aP[h][row][*]
    float* Hp = h1aP + (size_t)h * NN * 128;
    int c0 = tc * 4, c1 = 64 + tc * 4;
    float bvA[4], bvB[4];
#pragma unroll
    for (int j = 0; j < 4; j++) {
        bvA[j] = b1[h * FIN + c0 + j];                       // c0+j <= 63 < 114 always
        bvB[j] = (c1 + j < FIN) ? b1[h * FIN + c1 + j] : 0.f;
    }
#pragma unroll
    for (int r = 0; r < 4; r++) {
        int row = rb + tr * 4 + r;
        if (row >= NN) continue;
        float vA[4], vB[4];
#pragma unroll
        for (int j = 0; j < 4; j++) {
            float v = acc[r][j] + bvA[j];
            vA[j] = v > 0.f ? v : expm1f(v);
            float w = acc[r][j + 4] + bvB[j];
            vB[j] = (c1 + j < FIN) ? (w > 0.f ? w : expm1f(w)) : 0.f;
        }
        *(float4*)(Hp + (size_t)row * 128 + c0) = make_float4(vA[0], vA[1], vA[2], vA[3]);
        *(float4*)(Hp + (size_t)row * 128 + c1) = make_float4(vB[0], vB[1], vB[2], vB[3]);
    }
}

// ===== GEMM2 tiled: h2 = h1aP @ W2P, K=384 uniform (zeros baked in pads) =====
// grid 626 (mt=bx>>1, nb=(bx&1)*64), 256 thr; BM=64, BN=64, BK=32, 12 tiles.
__global__ __launch_bounds__(256) void k_gemm2t(const float* __restrict__ h1aP,
                                                const float* __restrict__ W2P,
                                                float* __restrict__ h2) {
    int mt = blockIdx.x >> 1, nb = (blockIdx.x & 1) * 64;
    int rb = mt * 64;
    int t = threadIdx.x;
    int tr = t >> 4, tc = t & 15;
    __shared__ float As[64][36];
    __shared__ float Bs[32][68];
    const float4 zf4 = make_float4(0.f, 0.f, 0.f, 0.f);
    int ar0 = t >> 3, ak0 = t & 7;
    int ar1 = 32 + ar0;
    int bk0 = t >> 4, bn0 = t & 15;
    int bk1 = 16 + bk0;
    // A k-index: global k = tile*32 + ak0*4 -> head h = k>>7, col = k&127
    auto loadA = [&](int row, int kg) -> float4 {
        if (row >= NN) return zf4;
        int h = kg >> 7, kc = kg & 127;
        return *(const float4*)(h1aP + ((size_t)h * NN + row) * 128 + kc);
    };
    float4 aR[2], bR[2];
    {
        int g0 = rb + ar0, g1 = rb + ar1;
        aR[0] = loadA(g0, ak0 * 4);
        aR[1] = loadA(g1, ak0 * 4);
        bR[0] = *(const float4*)(W2P + (size_t)bk0 * D2 + nb + bn0 * 4);
        bR[1] = *(const float4*)(W2P + (size_t)bk1 * D2 + nb + bn0 * 4);
    }
    float acc[4][4] = {};
    for (int tile = 0; tile < 12; tile++) {
        if (tile) __syncthreads();
        *(float4*)(&As[ar0][ak0 * 4]) = aR[0];
        *(float4*)(&As[ar1][ak0 * 4]) = aR[1];
        *(float4*)(&Bs[bk0][bn0 * 4]) = bR[0];
        *(float4*)(&Bs[bk1][bn0 * 4]) = bR[1];
        __syncthreads();
        if (tile < 11) {
            int k0 = (tile + 1) * 32;
            int g0 = rb + ar0, g1 = rb + ar1;
            aR[0] = loadA(g0, k0 + ak0 * 4);
            aR[1] = loadA(g1, k0 + ak0 * 4);
            bR[0] = *(const float4*)(W2P + (size_t)(k0 + bk0) * D2 + nb + bn0 * 4);
            bR[1] = *(const float4*)(W2P + (size_t)(k0 + bk1) * D2 + nb + bn0 * 4);
        }
#pragma unroll
        for (int kc = 0; kc < 32; kc += 4) {
            float a4[4][4];
#pragma unroll
            for (int r = 0; r < 4; r++)
                *(float4*)a4[r] = *(const float4*)(&As[tr * 4 + r][kc]);
#pragma unroll
            for (int kk = 0; kk < 4; kk++) {
                float4 b0 = *(const float4*)(&Bs[kc + kk][tc * 4]);
#pragma unroll
                for (int r = 0; r < 4; r++) {
                    float av = a4[r][kk];
                    acc[r][0] += av * b0.x; acc[r][1] += av * b0.y;
                    acc[r][2] += av * b0.z; acc[r][3] += av * b0.w;
                }
            }
        }
    }
#pragma unroll
    for (int r = 0; r < 4; r++) {
        int row = rb + tr * 4 + r;
        if (row < NN)
            *(float4*)(&h2[(size_t)row * D2 + nb + tc * 4]) =
                make_float4(acc[r][0], acc[r][1], acc[r][2], acc[r][3]);
    }
}

// ===== alpha2: per-node dot(h2_row, a_src2/a_dst2) =====
__global__ __launch_bounds__(256) void k_alpha2(const float* __restrict__ h2,
                                                const float* __restrict__ aS,
                                                const float* __restrict__ aD,
                                                float* __restrict__ as2,
                                                float* __restrict__ ad2) {
    int n = blockIdx.x * 4 + (threadIdx.x >> 6);
    int l = threadIdx.x & 63;
    if (n >= NN) return;
    float v0 = h2[(size_t)n * D2 + l], v1 = h2[(size_t)n * D2 + 64 + l];
    float ps = v0 * aS[l] + v1 * aS[64 + l];
    float pd = v0 * aD[l] + v1 * aD[64 + l];
    for (int o = 32; o > 0; o >>= 1) {
        ps += __shfl_down(ps, o);
        pd += __shfl_down(pd, o);
    }
    if (l == 0) {
        as2[n] = ps;
        ad2[n] = pd;
    }
}

// ===== layer-2: fused softmax+aggregate+relu+POOL (atomicMax into poolbuf) =====
__global__ __launch_bounds__(128) void k_agg2f(const float* __restrict__ h2,
                                               const float* __restrict__ as2,
                                               const float* __restrict__ ad2,
                                               const int* __restrict__ off,
                                               const int* __restrict__ csr_src,
                                               const float* __restrict__ b2,
                                               unsigned* __restrict__ poolbuf) {
    int n = blockIdx.x, t = threadIdx.x;
    int e0 = off[n], e1 = off[n + 1];
    float adv = ad2[n];
    __shared__ int ssrc[64];
    __shared__ float sw[64];
    __shared__ float red[64];
    float acc = 0.f, ps = 0.f;
    for (int base = e0; base < e1; base += 64) {
        int c = min(64, e1 - base);
        __syncthreads();
        if (t < c) {
            int s = csr_src[base + t];
            ssrc[t] = s;
            float w = __expf(lrelu(as2[s] + adv));
            sw[t] = w;
            ps += w;
        }
        __syncthreads();
        for (int j = 0; j < c; j++) acc += h2[(size_t)ssrc[j] * D2 + t] * sw[j];
    }
    __syncthreads();
    if (t < 64) red[t] = ps;
    __syncthreads();
    for (int sr = 32; sr > 0; sr >>= 1) {
        if (t < sr) red[t] += red[t + sr];
        __syncthreads();
    }
    float v = fmaxf(acc / red[0] + b2[t], 0.f);
    int g = (int)(((long long)n * GG) / NN);   // batch[n] = n*G//N
    atomicMax(&poolbuf[g * D2 + t], fenc(v));
}

// ===== MLP head =====
__global__ __launch_bounds__(128) void k_mlp(const unsigned* __restrict__ poolbuf,
                                             const float* __restrict__ Wg,
                                             const float* __restrict__ bg,
                                             const float* __restrict__ Wf1,
                                             const float* __restrict__ bf1,
                                             const float* __restrict__ Wf2,
                                             const float* __restrict__ bf2,
                                             const float* __restrict__ Wo,
                                             const float* __restrict__ bo,
                                             float* __restrict__ out) {
    int g = blockIdx.x;
    int t = threadIdx.x;
    __shared__ float pool[D2];
    __shared__ float a1[64];
    __shared__ float a2[32];
    __shared__ float a3[16];
    pool[t] = fdec(poolbuf[g * D2 + t]);
    __syncthreads();
    if (t < 64) {
        float acc = bg[t];
        for (int k = 0; k < D2; k++) acc += pool[k] * Wg[k * 64 + t];
        a1[t] = fmaxf(acc, 0.f);
    }
    __syncthreads();
    if (t < 32) {
        float acc = bf1[t];
        for (int k = 0; k < 64; k++) acc += a1[k] * Wf1[k * 32 + t];
        a2[t] = fmaxf(acc, 0.f);
    }
    __syncthreads();
    if (t < 16) {
        float acc = bf2[t];
        for (int k = 0; k < 32; k++) acc += a2[k] * Wf2[k * 16 + t];
        a3[t] = fmaxf(acc, 0.f);
    }
    __syncthreads();
    if (t == 0) {
        float acc = bo[0];
        for (int k = 0; k < 16; k++) acc += a3[k] * Wo[k];
        out[g] = acc;
    }
}

extern "C" void kernel_launch(void* const* d_in, const int* in_sizes, int n_in,
                              void* d_out, int out_size, void* d_ws, size_t ws_size,
                              hipStream_t stream) {
    const float* x = (const float*)d_in[0];
    const int* ei = (const int*)d_in[1];
    const float* W1 = (const float*)d_in[3];
    const float* aS1 = (const float*)d_in[4];
    const float* aD1 = (const float*)d_in[5];
    const float* b1 = (const float*)d_in[6];
    const float* W2 = (const float*)d_in[7];
    const float* aS2 = (const float*)d_in[8];
    const float* aD2 = (const float*)d_in[9];
    const float* b2 = (const float*)d_in[10];
    const float* Wg = (const float*)d_in[11];
    const float* bg = (const float*)d_in[12];
    const float* Wf1 = (const float*)d_in[13];
    const float* bf1 = (const float*)d_in[14];
    const float* Wf2 = (const float*)d_in[15];
    const float* bf2 = (const float*)d_in[16];
    const float* Wo = (const float*)d_in[17];
    const float* bo = (const float*)d_in[18];
    float* out = (float*)d_out;

    const int* src = ei;
    const int* dst = ei + EE;

    char* ws = (char*)d_ws;
    size_t o = 0;
    auto alloc = [&](size_t bytes) -> char* {
        char* p = ws + o;
        o += (bytes + 255) & ~(size_t)255;
        return p;
    };
    float* was = (float*)alloc((size_t)FIN * H1 * 4);
    float* wad = (float*)alloc((size_t)FIN * H1 * 4);
    float* W1P = (float*)alloc((size_t)H1 * 128 * 128 * 4);
    float* W2P = (float*)alloc((size_t)3 * 128 * 128 * 4);
    float* as1 = (float*)alloc((size_t)NN * H1 * 4);
    float* ad1 = (float*)alloc((size_t)NN * H1 * 4);
    int* cnt = (int*)alloc((size_t)NN * 4);
    int* off = (int*)alloc((size_t)(NN + 1) * 4);
    int* cur = (int*)alloc((size_t)NN * 4);
    int* csr_src = (int*)alloc((size_t)EE * 4);
    float* xaggP = (float*)alloc((size_t)H1 * NN * 128 * 4);
    float* h1aP = (float*)alloc((size_t)H1 * NN * 128 * 4);
    float* h2 = (float*)alloc((size_t)NN * D2 * 4);
    float* as2 = (float*)alloc((size_t)NN * 4);
    float* ad2 = (float*)alloc((size_t)NN * 4);
    unsigned* poolbuf = (unsigned*)alloc((size_t)GG * D2 * 4);
    (void)ws_size;

    hipMemsetAsync(cnt, 0, (size_t)NN * 4, stream);
    hipMemsetAsync(cur, 0, (size_t)NN * 4, stream);
    hipMemsetAsync(poolbuf, 0, (size_t)GG * D2 * 4, stream);

    const int EB = (EE + 255) / 256;

    k_wa<<<(2 * FIN * H1 + 255) / 256, 256, 0, stream>>>(W1, aS1, aD1, was, wad);
    k_prep1<<<(H1 * 128 * 128 + 255) / 256, 256, 0, stream>>>(W1, W1P);
    k_prep2<<<(3 * 128 * 128 + 255) / 256, 256, 0, stream>>>(W2, W2P);
    k_alpha1x<<<(NN + 3) / 4, 256, 0, stream>>>(x, was, wad, as1, ad1);
    k_count<<<EB, 256, 0, stream>>>(dst, cnt);
    k_scan<<<1, 1024, 0, stream>>>(cnt, off);
    k_scatter<<<EB, 256, 0, stream>>>(src, dst, off, cur, csr_src);
    k_aggx<<<NN, 128, 0, stream>>>(x, as1, ad1, off, csr_src, xaggP);
    k_gemm1t<<<dim3((NN + 63) / 64, H1), 256, 0, stream>>>(xaggP, W1P, b1, h1aP);
    k_gemm2t<<<((NN + 63) / 64) * 2, 256, 0, stream>>>(h1aP, W2P, h2);
    k_alpha2<<<(NN + 3) / 4, 256, 0, stream>>>(h2, aS2, aD2, as2, ad2);
    k_agg2f<<<NN, 128, 0, stream>>>(h2, as2, ad2, off, csr_src, b2, poolbuf);
    k_mlp<<<GG, 128, 0, stream>>>(poolbuf, Wg, bg, Wf1, bf1, Wf2, bf2, Wo, bo, out);
}